// Round 2
// baseline (931.424 us; speedup 1.0000x reference)
//
#include <hip/hip_runtime.h>
#include <hip/hip_bf16.h>

#define BB 64
#define TT 512
#define FF 1024
#define KK 64

// ---------------- Emission GEMM: em[row][k] = dot(X[row,:], W[k,:]) + b[k] ----------------
// 128-row x 64-col tile, 256 threads (4 waves). Lane = rg*16+cg: 16 lanes share
// each A read (LDS broadcast) -> fragment traffic ~6x lower, FMA-issue-bound.
#define EM_BM 128
#define EM_BF 64
#define LDSA 132   // 132*4 = 528 B row stride, 16B-aligned, ~2-way banks max
#define LDSB 68    // 272 B row stride

__global__ __launch_bounds__(256)
void emission_kernel(const float* __restrict__ X, const float* __restrict__ W,
                     const float* __restrict__ bias, float* __restrict__ em)
{
    __shared__ float As[EM_BF][LDSA];   // As[f][row]
    __shared__ float Bs[EM_BF][LDSB];   // Bs[f][col]
    const int tid  = threadIdx.x;
    const int row0 = blockIdx.x * EM_BM;
    const int wave = tid >> 6, lane = tid & 63;
    const int rg = lane >> 4, cg = lane & 15;
    const int r_base = wave * 32 + rg * 8;   // 8 rows per thread
    const int c_base = cg * 4;               // 4 cols per thread
    const int fq = tid & 15, rr = tid >> 4;  // staging coords

    float acc[8][4];
#pragma unroll
    for (int i = 0; i < 8; ++i)
#pragma unroll
        for (int jj = 0; jj < 4; ++jj) acc[i][jj] = 0.f;

    for (int f0 = 0; f0 < FF; f0 += EM_BF) {
#pragma unroll
        for (int p = 0; p < 8; ++p) {            // A tile: 128 rows x 64 f
            const int row = p * 16 + rr;
            float4 a = *(const float4*)(X + (size_t)(row0 + row) * FF + f0 + fq * 4);
            As[fq * 4 + 0][row] = a.x;
            As[fq * 4 + 1][row] = a.y;
            As[fq * 4 + 2][row] = a.z;
            As[fq * 4 + 3][row] = a.w;
        }
#pragma unroll
        for (int p = 0; p < 4; ++p) {            // B tile: 64 k x 64 f
            const int k = p * 16 + rr;
            float4 wv = *(const float4*)(W + (size_t)k * FF + f0 + fq * 4);
            Bs[fq * 4 + 0][k] = wv.x;
            Bs[fq * 4 + 1][k] = wv.y;
            Bs[fq * 4 + 2][k] = wv.z;
            Bs[fq * 4 + 3][k] = wv.w;
        }
        __syncthreads();
#pragma unroll 8
        for (int f = 0; f < EM_BF; ++f) {
            float4 a0 = *(const float4*)&As[f][r_base];
            float4 a1 = *(const float4*)&As[f][r_base + 4];
            float4 b  = *(const float4*)&Bs[f][c_base];
            acc[0][0] += a0.x * b.x; acc[0][1] += a0.x * b.y; acc[0][2] += a0.x * b.z; acc[0][3] += a0.x * b.w;
            acc[1][0] += a0.y * b.x; acc[1][1] += a0.y * b.y; acc[1][2] += a0.y * b.z; acc[1][3] += a0.y * b.w;
            acc[2][0] += a0.z * b.x; acc[2][1] += a0.z * b.y; acc[2][2] += a0.z * b.z; acc[2][3] += a0.z * b.w;
            acc[3][0] += a0.w * b.x; acc[3][1] += a0.w * b.y; acc[3][2] += a0.w * b.z; acc[3][3] += a0.w * b.w;
            acc[4][0] += a1.x * b.x; acc[4][1] += a1.x * b.y; acc[4][2] += a1.x * b.z; acc[4][3] += a1.x * b.w;
            acc[5][0] += a1.y * b.x; acc[5][1] += a1.y * b.y; acc[5][2] += a1.y * b.z; acc[5][3] += a1.y * b.w;
            acc[6][0] += a1.z * b.x; acc[6][1] += a1.z * b.y; acc[6][2] += a1.z * b.z; acc[6][3] += a1.z * b.w;
            acc[7][0] += a1.w * b.x; acc[7][1] += a1.w * b.y; acc[7][2] += a1.w * b.z; acc[7][3] += a1.w * b.w;
        }
        __syncthreads();
    }

    const float4 b4 = *(const float4*)(bias + c_base);
#pragma unroll
    for (int i = 0; i < 8; ++i) {
        float4 o;
        o.x = acc[i][0] + b4.x;
        o.y = acc[i][1] + b4.y;
        o.z = acc[i][2] + b4.z;
        o.w = acc[i][3] + b4.w;
        *(float4*)(em + (size_t)(row0 + r_base + i) * KK + c_base) = o;
    }
}

// ---------------- Viterbi: 4 waves per sequence; wave w owns prev-tags i in [16w,16w+16) ----
// lane j = next tag. Each wave keeps a bit-exact replica of score[j] in its lanes.
// Cross-wave combine via double-buffered LDS, ONE barrier per step.
// Backtrack: 8 segments x 64 steps; all-64-hypothesis replay (lane = hypothesis),
// waves process 2 segments each in parallel, then 8-step compose + parallel emit.
__global__ __launch_bounds__(256)
void viterbi_kernel(const float* __restrict__ em, const void* __restrict__ maskp,
                    const float* __restrict__ startT, const float* __restrict__ endT,
                    const float* __restrict__ trans, float* __restrict__ pred)
{
    const int b = blockIdx.x;
    const int tid = threadIdx.x;
    const int w = tid >> 6;     // wave id 0..3
    const int j = tid & 63;     // tag lane

    __shared__ unsigned char hist[TT][KK];     // 32 KB: best prev tag per (t,j)
    __shared__ unsigned char hypo[8][64][64];  // 32 KB: hypo[s][u][h] = tag at 64s+u given tag[t1(s)]=h
    __shared__ float pvals[2][4][KK];          // per-wave candidate values
    __shared__ int   pidx [2][4][KK];          // per-wave candidate indices

    // trans column slice for this wave's i-range: tc[q] = trans[16w+q][j]
    float tc[16];
#pragma unroll
    for (int q = 0; q < 16; ++q) tc[q] = trans[(w * 16 + q) * KK + j];

    // mask layout detection (lengths >= 256 so mask[0][1] is true):
    const unsigned char* m8 = (const unsigned char*)maskp;
    const int* m32 = (const int*)maskp;
    const bool u8m = (m8[1] != 0);

    const float* emb = em + (size_t)b * TT * KK;
    float score = startT[j] + emb[j];           // t = 0
    const float endv = endT[j];

    int p = 0;
    float e_cur = emb[KK + j];                                        // t = 1
    int   m_cur = u8m ? (int)m8[b * TT + 1] : m32[b * TT + 1];

    for (int t = 1; t < TT; ++t) {
        const int tn = (t + 1 < TT) ? (t + 1) : (TT - 1);
        float e_next = emb[(size_t)tn * KK + j];                      // prefetch
        int   m_next = u8m ? (int)m8[b * TT + tn] : m32[b * TT + tn];

        if (m_cur) {   // uniform across block
            float tv[16]; int ti[16];
#pragma unroll
            for (int q = 0; q < 16; ++q) {
                const float si = __uint_as_float(
                    (unsigned)__builtin_amdgcn_readlane((int)__float_as_uint(score), w * 16 + q));
                tv[q] = (si + tc[q]) + e_cur;    // reference association order
                ti[q] = w * 16 + q;
            }
            // contiguous-pair tree; >= keeps LEFT (lower index) => first-index argmax
#pragma unroll
            for (int n = 8; n >= 1; n >>= 1)
#pragma unroll
                for (int q = 0; q < n; ++q) {
                    const bool c = tv[2 * q] >= tv[2 * q + 1];
                    tv[q] = c ? tv[2 * q] : tv[2 * q + 1];
                    ti[q] = c ? ti[2 * q] : ti[2 * q + 1];
                }
            pvals[p][w][j] = tv[0];
            pidx [p][w][j] = ti[0];
            __syncthreads();
            float bv = pvals[p][0][j];
            int   bi = pidx [p][0][j];
#pragma unroll
            for (int ww = 1; ww < 4; ++ww) {
                const float v2 = pvals[p][ww][j];
                const int   i2 = pidx [p][ww][j];
                if (v2 > bv) { bv = v2; bi = i2; }   // strict >: lower wave wins ties
            }
            score = bv;                               // identical in all 4 replicas
            if (w == 0) hist[t][j] = (unsigned char)bi;
            p ^= 1;
        } else {
            if (w == 0) hist[t][j] = (unsigned char)j;  // identity carry
        }
        e_cur = e_next; m_cur = m_next;
    }

    score += endv;
    // first-index argmax over 64 lanes (uniform in every thread)
    float bm = __uint_as_float((unsigned)__builtin_amdgcn_readlane((int)__float_as_uint(score), 0));
    int bt = 0;
#pragma unroll
    for (int i = 1; i < KK; ++i) {
        const float si = __uint_as_float((unsigned)__builtin_amdgcn_readlane((int)__float_as_uint(score), i));
        if (si > bm) { bm = si; bt = i; }
    }

    __syncthreads();   // hist complete

    // Phase A: all-hypothesis segment replay; wave w -> segments 2w, 2w+1
#pragma unroll
    for (int ss = 0; ss < 2; ++ss) {
        const int s = w * 2 + ss;
        int tag = j;
        if (s == 7) {
            hypo[7][63][j] = (unsigned char)j;            // tag at t=511
            for (int t = TT - 1; t >= 7 * 64 + 1; --t) {
                tag = hist[t][tag];
                hypo[7][t - 1 - 7 * 64][j] = (unsigned char)tag;
            }
        } else {
            for (int t = (s + 1) * 64; t >= s * 64 + 1; --t) {
                tag = hist[t][tag];
                hypo[s][t - 1 - s * 64][j] = (unsigned char)tag;
            }
        }
    }
    __syncthreads();

    // Phase B: compose boundary tags (uniform on all threads; broadcast reads)
    int rows_[8];
    rows_[7] = bt;
#pragma unroll
    for (int s = 6; s >= 0; --s) rows_[s] = hypo[s + 1][0][rows_[s + 1]];

    // Phase C: emit; wave w -> segments 2w, 2w+1; lane j -> time 64s+j
    float* pb = pred + (size_t)b * TT;
#pragma unroll
    for (int ss = 0; ss < 2; ++ss) {
        const int s = w * 2 + ss;
        pb[s * 64 + j] = (float)hypo[s][j][rows_[s]];
    }
}

extern "C" void kernel_launch(void* const* d_in, const int* in_sizes, int n_in,
                              void* d_out, int out_size, void* d_ws, size_t ws_size,
                              hipStream_t stream) {
    const float* X      = (const float*)d_in[0];
    const void*  mask   = d_in[1];
    const float* W      = (const float*)d_in[2];
    const float* bias   = (const float*)d_in[3];
    const float* startT = (const float*)d_in[4];
    const float* endT   = (const float*)d_in[5];
    const float* trans  = (const float*)d_in[6];

    float* em   = (float*)d_out;
    float* pred = (float*)d_out + (size_t)BB * TT * KK;

    emission_kernel<<<(BB * TT) / EM_BM, 256, 0, stream>>>(X, W, bias, em);
    viterbi_kernel<<<BB, 256, 0, stream>>>(em, mask, startT, endT, trans, pred);
}